// Round 5
// baseline (337.949 us; speedup 1.0000x reference)
//
#include <hip/hip_runtime.h>
#include <math.h>

// Sparsemax rows: out = max(z - tau, 0), tau s.t. sum(max(z - tau, 0)) = 1.
//
// ONE WAVE PER ROW, SINGLE STREAMING PASS + tiny state:
// Round 3/4 lesson: asking for z[64]/lane makes the compiler rematerialize
// the row from global for every Michelot iteration (VGPR_Count=56 proved it;
// ~1.6 GB of L3 re-reads = the 119 us wall). Fix: never keep the row live.
//
// Pass 1: stream row once, per-lane TOP-8 buffer via branchless min/max
//   insertion chain (b[] sorted descending). tau >= zmax-1, so the support
//   is a subset of {z > zmax-1}; the wave's 512 buffered values cover it
//   unless some lane's 8th-best > zmax-1 (ballot-detected; exact streaming
//   fallback, essentially never taken for Gaussian rows).
// tau: Michelot over the 8 candidate regs/lane -> EXACT tau, ~4 iterations.
// Pass 2: re-read row (L2/L3-warm) and write out.

constexpr int S   = 4096;
constexpr int TPB = 256;
constexpr int NW  = TPB / 64;   // 4 waves (= 4 rows) per block
constexpr int NC  = S / 64 / 4; // 16 float4 chunks per lane
constexpr int TK  = 8;          // top-K per lane

#define NEGBIG (-1e30f)

__global__ __launch_bounds__(TPB) void sparsemax_kernel(
    const float* __restrict__ scores,
    const int*   __restrict__ mask,
    float*       __restrict__ out)
{
    const int tid  = threadIdx.x;
    const int lane = tid & 63;
    const int wid  = tid >> 6;
    const int row  = blockIdx.x * NW + wid;

    const float4* srow4 = reinterpret_cast<const float4*>(scores + (size_t)row * S);
    const int4*   mrow4 = reinterpret_cast<const int4*>(mask + (size_t)row * S);
    float4*       orow4 = reinterpret_cast<float4*>(out + (size_t)row * S);

    // ---- pass 1: stream row, maintain per-lane top-8 (descending) ----
    float b[TK];
    #pragma unroll
    for (int i = 0; i < TK; ++i) b[i] = NEGBIG;

    #pragma unroll
    for (int c = 0; c < NC; ++c) {
        const float4 s4 = srow4[c * 64 + lane];
        const int4   m4 = mrow4[c * 64 + lane];
        float v[4];
        v[0] = m4.x ? s4.x : NEGBIG;
        v[1] = m4.y ? s4.y : NEGBIG;
        v[2] = m4.z ? s4.z : NEGBIG;
        v[3] = m4.w ? s4.w : NEGBIG;
        #pragma unroll
        for (int u = 0; u < 4; ++u) {
            float x = v[u];
            #pragma unroll
            for (int i = 0; i < TK; ++i) {       // branchless sorted insert
                const float hi = fmaxf(b[i], x);
                x    = fminf(b[i], x);
                b[i] = hi;
            }
        }
    }

    // ---- zmax across wave ----
    float m = b[0];
    #pragma unroll
    for (int o = 1; o < 64; o <<= 1) m = fmaxf(m, __shfl_xor(m, o, 64));
    const float zmax = m;
    const float t0 = zmax - 1.0f;

    float tau;
    const unsigned long long overflow = __ballot(b[TK - 1] > t0);
    if (overflow == 0ull) {
        // ---- Michelot over candidate registers (exact tau) ----
        float t = t0;
        int cprev = -1;
        #pragma unroll 1
        for (int it = 0; it < 40; ++it) {
            float s = 0.0f;
            int   c = 0;
            #pragma unroll
            for (int i = 0; i < TK; ++i) {
                const bool in = b[i] > t;
                s += in ? b[i] : 0.0f;
                c += in ? 1 : 0;
            }
            #pragma unroll
            for (int o = 1; o < 64; o <<= 1) {
                s += __shfl_xor(s, o, 64);
                c += __shfl_xor(c, o, 64);
            }
            if (c == cprev) break;
            t = (s - 1.0f) / (float)c;     // c >= 1 (zmax > t0 always)
            cprev = c;
        }
        tau = t;
    } else {
        // ---- exact fallback: streaming Michelot (rare; L2/L3-warm) ----
        float t = t0;
        int cprev = -1;
        #pragma unroll 1
        for (int it = 0; it < 40; ++it) {
            float s = 0.0f;
            int   c = 0;
            #pragma unroll 1
            for (int ch = 0; ch < NC; ++ch) {
                const float4 s4 = srow4[ch * 64 + lane];
                const int4   m4 = mrow4[ch * 64 + lane];
                const float w0 = m4.x ? s4.x : NEGBIG;
                const float w1 = m4.y ? s4.y : NEGBIG;
                const float w2 = m4.z ? s4.z : NEGBIG;
                const float w3 = m4.w ? s4.w : NEGBIG;
                if (w0 > t) { s += w0; ++c; }
                if (w1 > t) { s += w1; ++c; }
                if (w2 > t) { s += w2; ++c; }
                if (w3 > t) { s += w3; ++c; }
            }
            #pragma unroll
            for (int o = 1; o < 64; o <<= 1) {
                s += __shfl_xor(s, o, 64);
                c += __shfl_xor(c, o, 64);
            }
            if (c == cprev) break;
            t = (s - 1.0f) / (float)c;
            cprev = c;
        }
        tau = t;
    }

    // ---- pass 2: re-read row (cache-warm), write out ----
    #pragma unroll
    for (int c = 0; c < NC; ++c) {
        const float4 s4 = srow4[c * 64 + lane];
        const int4   m4 = mrow4[c * 64 + lane];
        float4 o4;
        o4.x = m4.x ? fmaxf(s4.x - tau, 0.0f) : 0.0f;
        o4.y = m4.y ? fmaxf(s4.y - tau, 0.0f) : 0.0f;
        o4.z = m4.z ? fmaxf(s4.z - tau, 0.0f) : 0.0f;
        o4.w = m4.w ? fmaxf(s4.w - tau, 0.0f) : 0.0f;
        orow4[c * 64 + lane] = o4;
    }
}

extern "C" void kernel_launch(void* const* d_in, const int* in_sizes, int n_in,
                              void* d_out, int out_size, void* d_ws, size_t ws_size,
                              hipStream_t stream) {
    const float* scores = (const float*)d_in[0];
    const int*   mask   = (const int*)d_in[1];
    float*       out    = (float*)d_out;
    const int B = in_sizes[0] / S;  // 8192
    sparsemax_kernel<<<dim3(B / NW), dim3(TPB), 0, stream>>>(scores, mask, out);
}

// Round 6
// 312.774 us; speedup vs baseline: 1.0805x; 1.0805x over previous
//
#include <hip/hip_runtime.h>
#include <math.h>

// Sparsemax rows: out = max(z - tau, 0), tau s.t. sum(max(z - tau, 0)) = 1.
//
// ROUND 6: attack memory-level parallelism. Rounds 1-5 all landed ~120-145us
// with nothing saturated; per-wave arithmetic (43k cyc/wave) says loads were
// ~2-deep in flight (VGPR-limited + serial insertion chain consuming them).
// Fix: global_load_lds DMA (no VGPR cost) -- issue ALL 16 score chunks + all
// 16 mask loads back-to-back (32 outstanding/wave), one vmcnt(0) drain, then
// everything is LDS-local:
//   pass A: apply mask in place + zmax (tree max, no serial chain)
//   pass B: ballot-compact candidates {z > zmax-1} (superset of support;
//           order-free) into 256-entry LDS array
//   Michelot on 4 regs/lane -> EXACT tau (~4 iters)
//   epilogue: LDS -> max(z-tau,0) -> global stores
// One wave per block: zero barriers. LDS ~17KB -> 9 waves/CU, 32 reqs in
// flight each = ~150KB outstanding/CU >> ~20KB needed to saturate HBM.

constexpr int S   = 4096;
constexpr int NCH = S / 256;    // 16 chunks (64 lanes x float4)
constexpr int CAP = 256;        // candidate capacity (4 regs/lane)

#define NEGBIG (-1e30f)

typedef __attribute__((address_space(3))) void  lds_void_t;
typedef __attribute__((address_space(1))) void  gbl_void_t;

__global__ __launch_bounds__(64) void sparsemax_kernel(
    const float* __restrict__ scores,
    const int*   __restrict__ mask,
    float*       __restrict__ out)
{
    const int lane = threadIdx.x;   // 64-thread block = 1 wave = 1 row
    const int row  = blockIdx.x;

    __shared__ __align__(16) float zb[S];     // 16 KB masked row
    __shared__ float cand[CAP];               // 1 KB candidates

    const float4* srow4 = reinterpret_cast<const float4*>(scores + (size_t)row * S);
    const int4*   mrow4 = reinterpret_cast<const int4*>(mask + (size_t)row * S);
    float4*       orow4 = reinterpret_cast<float4*>(out + (size_t)row * S);

    // ---- 1) async DMA: scores -> LDS, 16B per lane per chunk ----
    #pragma unroll
    for (int c = 0; c < NCH; ++c) {
        __builtin_amdgcn_global_load_lds(
            (const gbl_void_t*)(srow4 + c * 64 + lane),
            (lds_void_t*)(zb + c * 256 + lane * 4),
            16, 0, 0);
    }
    // ---- 2) mask stream: 16 int4 loads, all issued behind the DMAs ----
    int4 mreg[NCH];
    #pragma unroll
    for (int c = 0; c < NCH; ++c) mreg[c] = mrow4[c * 64 + lane];

    // ---- 3) single drain: vmcnt(0) (exp=7, lgkm=15 untouched) ----
    __builtin_amdgcn_s_waitcnt(0x0F70);

    // ---- 4) pass A: apply mask in place + row max (tree, no serial chain) ----
    float m = NEGBIG;
    #pragma unroll
    for (int c = 0; c < NCH; ++c) {
        float4 z4 = *reinterpret_cast<float4*>(&zb[c * 256 + lane * 4]);
        const int4 m4 = mreg[c];
        z4.x = m4.x ? z4.x : NEGBIG;
        z4.y = m4.y ? z4.y : NEGBIG;
        z4.z = m4.z ? z4.z : NEGBIG;
        z4.w = m4.w ? z4.w : NEGBIG;
        *reinterpret_cast<float4*>(&zb[c * 256 + lane * 4]) = z4;
        m = fmaxf(m, fmaxf(fmaxf(z4.x, z4.y), fmaxf(z4.z, z4.w)));
    }
    #pragma unroll
    for (int o = 1; o < 64; o <<= 1) m = fmaxf(m, __shfl_xor(m, o, 64));
    const float zmax = m;
    const float t0   = zmax - 1.0f;   // tau >= t0; support subset of {z > t0}

    // ---- 5) pass B: ballot-compact candidates (order-free) ----
    const unsigned long long lt = (1ull << lane) - 1ull;
    unsigned cnt = 0;                 // wave-uniform
    #pragma unroll
    for (int c = 0; c < NCH; ++c) {
        const float4 z4 = *reinterpret_cast<const float4*>(&zb[c * 256 + lane * 4]);
        const float v0 = z4.x, v1 = z4.y, v2 = z4.z, v3 = z4.w;
        const unsigned long long b0 = __ballot(v0 > t0);
        const unsigned long long b1 = __ballot(v1 > t0);
        const unsigned long long b2 = __ballot(v2 > t0);
        const unsigned long long b3 = __ballot(v3 > t0);
        if ((b0 | b1 | b2 | b3) == 0ull) continue;   // uniform skip (common)
        const unsigned p0 = (unsigned)__popcll(b0);
        const unsigned p1 = (unsigned)__popcll(b1);
        const unsigned p2 = (unsigned)__popcll(b2);
        if (v0 > t0) { const unsigned i = cnt + (unsigned)__popcll(b0 & lt);
                       if (i < CAP) cand[i] = v0; }
        if (v1 > t0) { const unsigned i = cnt + p0 + (unsigned)__popcll(b1 & lt);
                       if (i < CAP) cand[i] = v1; }
        if (v2 > t0) { const unsigned i = cnt + p0 + p1 + (unsigned)__popcll(b2 & lt);
                       if (i < CAP) cand[i] = v2; }
        if (v3 > t0) { const unsigned i = cnt + p0 + p1 + p2 + (unsigned)__popcll(b3 & lt);
                       if (i < CAP) cand[i] = v3; }
        cnt += p0 + p1 + p2 + (unsigned)__popcll(b3);
    }

    // ---- 6) exact tau via Michelot ----
    float tau;
    if (cnt <= (unsigned)CAP) {
        float w[CAP / 64];
        #pragma unroll
        for (int i = 0; i < CAP / 64; ++i) {
            const unsigned id = (unsigned)lane + 64u * i;
            w[i] = (id < cnt) ? cand[id] : NEGBIG;
        }
        float t = t0; int cprev = -1;
        #pragma unroll 1
        for (int it = 0; it < 40; ++it) {
            float s = 0.0f; int c = 0;
            #pragma unroll
            for (int i = 0; i < CAP / 64; ++i) {
                const bool in = w[i] > t;
                s += in ? w[i] : 0.0f;
                c += in ? 1 : 0;
            }
            #pragma unroll
            for (int o = 1; o < 64; o <<= 1) {
                s += __shfl_xor(s, o, 64);
                c += __shfl_xor(c, o, 64);
            }
            if (c == cprev) break;
            t = (s - 1.0f) / (float)c;    // c >= 1 (zmax > t0)
            cprev = c;
        }
        tau = t;
    } else {
        // pathological fallback: Michelot over full LDS row
        float t = t0; int cprev = -1;
        #pragma unroll 1
        for (int it = 0; it < 40; ++it) {
            float s = 0.0f; int c = 0;
            #pragma unroll 1
            for (int ch = 0; ch < NCH; ++ch) {
                const float4 z4 = *reinterpret_cast<const float4*>(&zb[ch * 256 + lane * 4]);
                if (z4.x > t) { s += z4.x; ++c; }
                if (z4.y > t) { s += z4.y; ++c; }
                if (z4.z > t) { s += z4.z; ++c; }
                if (z4.w > t) { s += z4.w; ++c; }
            }
            #pragma unroll
            for (int o = 1; o < 64; o <<= 1) {
                s += __shfl_xor(s, o, 64);
                c += __shfl_xor(c, o, 64);
            }
            if (c == cprev) break;
            t = (s - 1.0f) / (float)c;
            cprev = c;
        }
        tau = t;
    }

    // ---- 7) epilogue: LDS -> out ----
    #pragma unroll
    for (int c = 0; c < NCH; ++c) {
        const float4 z4 = *reinterpret_cast<const float4*>(&zb[c * 256 + lane * 4]);
        float4 o4;
        o4.x = fmaxf(z4.x - tau, 0.0f);
        o4.y = fmaxf(z4.y - tau, 0.0f);
        o4.z = fmaxf(z4.z - tau, 0.0f);
        o4.w = fmaxf(z4.w - tau, 0.0f);
        orow4[c * 64 + lane] = o4;
    }
}

extern "C" void kernel_launch(void* const* d_in, const int* in_sizes, int n_in,
                              void* d_out, int out_size, void* d_ws, size_t ws_size,
                              hipStream_t stream) {
    const float* scores = (const float*)d_in[0];
    const int*   mask   = (const int*)d_in[1];
    float*       out    = (float*)d_out;
    const int B = in_sizes[0] / S;  // 8192 rows, one wave-block each
    sparsemax_kernel<<<dim3(B), dim3(64), 0, stream>>>(scores, mask, out);
}